// Round 6
// baseline (1094.310 us; speedup 1.0000x reference)
//
#include <hip/hip_runtime.h>
#include <hip/hip_bf16.h>
#include <hip/hip_fp16.h>

#define B2F(x) __bfloat162float(x)
#define F2B(x) __float2bfloat16(x)

typedef __bf16 bf16x8 __attribute__((ext_vector_type(8)));
typedef float floatx4 __attribute__((ext_vector_type(4)));

static constexpr int MROWS = 50176;   // 512 windows * 98 tokens
static constexpr int CDIM  = 256;
static constexpr int MCHUNK = 6272;   // MROWS / 8 for MLP chunking

enum { MODE_BF16 = 0, MODE_OFFAW = 1, MODE_REVERSE = 3, MODE_GELU = 4, MODE_FC2 = 5 };

// ---------------- helpers ----------------

__device__ __forceinline__ float block_sum256(float v, float* s4, int tid) {
#pragma unroll
    for (int off = 32; off > 0; off >>= 1) v += __shfl_down(v, off, 64);
    if ((tid & 63) == 0) s4[tid >> 6] = v;
    __syncthreads();
    float r = s4[0] + s4[1] + s4[2] + s4[3];
    __syncthreads();
    return r;
}

__device__ __forceinline__ void win_decode(int r, int& tok) {
    int w = r / 98, n = r - w * 98;
    int dB = w >> 6, hB = (w >> 3) & 7, wB = w & 7;
    int z = n / 49, n2 = n - z * 49, yy = n2 / 7, xx = n2 - yy * 7;
    tok = ((dB * 2 + z) * 56 + hB * 7 + yy) * 56 + wB * 7 + xx;
}

// ---------------- small kernels ----------------

// weight transpose + f32->bf16: src (K,N) f32 row-major -> dst (N,K) bf16
__global__ void transpose_kernel(const float* __restrict__ src,
                                 __hip_bfloat16* __restrict__ dst, int K, int N) {
    int i = blockIdx.x * 256 + threadIdx.x;
    if (i >= K * N) return;
    int nn = i / K, kk = i - nn * K;
    dst[(size_t)nn * K + kk] = F2B(src[(size_t)kk * N + nn]);
}

// csum[n] = sum_k W[k,n] over the transposed (N=128,K=256) off/aw weight
__global__ void colsum_kernel(const __hip_bfloat16* __restrict__ wT,
                              float* __restrict__ csum) {
    int n = threadIdx.x;
    if (n >= 128) return;
    float s = 0.f;
    for (int k = 0; k < 256; ++k) s += B2F(wT[n * 256 + k]);
    csum[n] = s;
}

// diag of PositionEmbeddingSine per (window, token)
__global__ void diag_kernel(const float* __restrict__ mask,
                            float* __restrict__ diag) {
    int r = blockIdx.x * 256 + threadIdx.x;
    if (r >= MROWS) return;
    int n = r % 98;
    int z = n / 49, n2 = n - z * 49, yy = n2 / 7, xx = n2 - yy * 7;
    const float* mb = mask + (size_t)r * 98;
    float m = mb[z * 49 + yy * 7 + xx];
    float sz = 0.f, sy = 0.f, sx = 0.f;
    for (int k = 0; k <= z; ++k)  sz += mb[k * 49 + yy * 7 + xx];
    for (int k = 0; k <= yy; ++k) sy += mb[z * 49 + k * 7 + xx];
    for (int k = 0; k <= xx; ++k) sx += mb[z * 49 + yy * 7 + k];
    const float PI = 3.14159265358979323846f;
    diag[r] = m * (sinf(sx * m / PI) + sinf(sy * m) + sz * m / PI);
}

// LN1 over original x (f32) -> windowed xw (bf16)
__global__ __launch_bounds__(256) void ln1_kernel(
    const float* __restrict__ x,
    const float* __restrict__ g, const float* __restrict__ b,
    __hip_bfloat16* __restrict__ xw) {
    __shared__ float s4[4];
    int r = blockIdx.x, c = threadIdx.x;
    int tok; win_decode(r, tok);
    float v = x[(size_t)tok * CDIM + c];
    float mean = block_sum256(v, s4, c) * (1.f / 256.f);
    float d = v - mean;
    float var = block_sum256(d * d, s4, c) * (1.f / 256.f);
    xw[(size_t)r * CDIM + c] = F2B(d * rsqrtf(var + 1e-5f) * g[c] + b[c]);
}

// recompute LN1(x), add attn (windowed), second LN -> a2
__global__ __launch_bounds__(256) void ln_a_kernel(
    const float* __restrict__ x, const __hip_bfloat16* __restrict__ attn,
    const float* __restrict__ g1, const float* __restrict__ b1,
    const float* __restrict__ g, const float* __restrict__ b,
    __hip_bfloat16* __restrict__ a2) {
    __shared__ float s4[4];
    int r = blockIdx.x, c = threadIdx.x;
    int tok; win_decode(r, tok);
    float v = x[(size_t)tok * CDIM + c];
    float mean = block_sum256(v, s4, c) * (1.f / 256.f);
    float d = v - mean;
    float var = block_sum256(d * d, s4, c) * (1.f / 256.f);
    float xw = d * rsqrtf(var + 1e-5f) * g1[c] + b1[c];
    float t = xw + B2F(attn[(size_t)r * CDIM + c]);
    float mean2 = block_sum256(t, s4, c) * (1.f / 256.f);
    float d2 = t - mean2;
    float var2 = block_sum256(d2 * d2, s4, c) * (1.f / 256.f);
    a2[(size_t)r * CDIM + c] = F2B(d2 * rsqrtf(var2 + 1e-5f) * g[c] + b[c]);
}

// LN over f32 trunk (token order) -> hin bf16
__global__ __launch_bounds__(256) void ln2_kernel(
    const float* __restrict__ xres,
    const float* __restrict__ g, const float* __restrict__ b,
    __hip_bfloat16* __restrict__ hin) {
    __shared__ float s4[4];
    int r = blockIdx.x, c = threadIdx.x;
    size_t i = (size_t)r * CDIM + c;
    float v = xres[i];
    float mean = block_sum256(v, s4, c) * (1.f / 256.f);
    float d = v - mean;
    float var = block_sum256(d * d, s4, c) * (1.f / 256.f);
    hin[i] = F2B(d * rsqrtf(var + 1e-5f) * g[c] + b[c]);
}

// softmax over NP + trilinear sample + weighted sum -> attn_in
__global__ __launch_bounds__(256) void sample_kernel(
    const __half* __restrict__ offaw,           // M x 128 (96 off | 32 aw)
    const __hip_bfloat16* __restrict__ value,   // M x 256
    __hip_bfloat16* __restrict__ attn_in) {     // M x 256
    int r = blockIdx.x, c = threadIdx.x;
    int h = c >> 5;
    int w = r / 98, n = r - w * 98;
    int z = n / 49, n2 = n - z * 49, yy = n2 / 7, xx = n2 - yy * 7;
    const __half* orow = offaw + (size_t)r * 128;
    float l0 = __half2float(orow[96 + h * 4 + 0]);
    float l1 = __half2float(orow[96 + h * 4 + 1]);
    float l2 = __half2float(orow[96 + h * 4 + 2]);
    float l3 = __half2float(orow[96 + h * 4 + 3]);
    float mx = fmaxf(fmaxf(l0, l1), fmaxf(l2, l3));
    float e[4];
    e[0] = expf(l0 - mx); e[1] = expf(l1 - mx); e[2] = expf(l2 - mx); e[3] = expf(l3 - mx);
    float inv = 1.f / (e[0] + e[1] + e[2] + e[3]);
    const __hip_bfloat16* vbase = value + (size_t)(w * 98) * CDIM + c;
    float acc = 0.f;
#pragma unroll
    for (int p = 0; p < 4; ++p) {
        float ox = __half2float(orow[h * 12 + p * 3 + 0]);
        float oy = __half2float(orow[h * 12 + p * 3 + 1]);
        float oz = __half2float(orow[h * 12 + p * 3 + 2]);
        float px = (float)xx + ox, py = (float)yy + oy, pz = (float)z + oz;
        float fx0 = floorf(px), fy0 = floorf(py), fz0 = floorf(pz);
        int ix = (int)fx0, iy = (int)fy0, iz = (int)fz0;
        float fx = px - fx0, fy = py - fy0, fz = pz - fz0;
        float wp = e[p] * inv;
        for (int dz = 0; dz < 2; ++dz) {
            int zi = iz + dz; if (zi < 0 || zi >= 2) continue;
            float wz = dz ? fz : 1.f - fz;
            for (int dy = 0; dy < 2; ++dy) {
                int yi = iy + dy; if (yi < 0 || yi >= 7) continue;
                float wy = dy ? fy : 1.f - fy;
                for (int dx = 0; dx < 2; ++dx) {
                    int xi = ix + dx; if (xi < 0 || xi >= 7) continue;
                    float wxw = dx ? fx : 1.f - fx;
                    acc += (wp * wz * wy * wxw) * B2F(vbase[(size_t)(zi * 49 + yi * 7 + xi) * CDIM]);
                }
            }
        }
    }
    attn_in[(size_t)r * CDIM + c] = F2B(acc);
}

// ---------------- MFMA GEMM: C[M,N] = A[M,K] * Bt[N,K]^T + bias ----------------

template <int MODE>
__global__ __launch_bounds__(256) void gemm_bt(
    const __hip_bfloat16* __restrict__ A,
    const __hip_bfloat16* __restrict__ Bt,
    const int N, const int K,
    const float* __restrict__ bias0,
    const float* __restrict__ bias1,
    void* C,
    const void* extra,
    const float* __restrict__ csum) {
    __shared__ __align__(16) __hip_bfloat16 As[128 * 32];
    __shared__ __align__(16) __hip_bfloat16 Bs[128 * 32];
    const int tid  = threadIdx.x;
    const int lane = tid & 63;
    const int wave = tid >> 6;
    const int wm = (wave >> 1) * 64;
    const int wn = (wave & 1) * 64;
    const int row0 = blockIdx.x * 128;
    const int col0 = blockIdx.y * 128;
    const int l15 = lane & 15;
    const int quad = lane >> 4;

    floatx4 acc[4][4] = {};

    const int sr = tid >> 2;
    const int sk = (tid & 3) * 8;

    const __hip_bfloat16* Ab = A + (size_t)row0 * K;
    const __hip_bfloat16* Bb = Bt + (size_t)col0 * K;

    for (int k0 = 0; k0 < K; k0 += 32) {
        *reinterpret_cast<uint4*>(&As[sr * 32 + sk]) =
            *reinterpret_cast<const uint4*>(&Ab[(size_t)sr * K + k0 + sk]);
        *reinterpret_cast<uint4*>(&As[(sr + 64) * 32 + sk]) =
            *reinterpret_cast<const uint4*>(&Ab[(size_t)(sr + 64) * K + k0 + sk]);
        *reinterpret_cast<uint4*>(&Bs[sr * 32 + sk]) =
            *reinterpret_cast<const uint4*>(&Bb[(size_t)sr * K + k0 + sk]);
        *reinterpret_cast<uint4*>(&Bs[(sr + 64) * 32 + sk]) =
            *reinterpret_cast<const uint4*>(&Bb[(size_t)(sr + 64) * K + k0 + sk]);
        __syncthreads();
        bf16x8 af[4], bfg[4];
#pragma unroll
        for (int i = 0; i < 4; ++i)
            af[i] = *reinterpret_cast<const bf16x8*>(&As[(wm + i * 16 + l15) * 32 + quad * 8]);
#pragma unroll
        for (int j = 0; j < 4; ++j)
            bfg[j] = *reinterpret_cast<const bf16x8*>(&Bs[(wn + j * 16 + l15) * 32 + quad * 8]);
#pragma unroll
        for (int i = 0; i < 4; ++i)
#pragma unroll
            for (int j = 0; j < 4; ++j)
                acc[i][j] = __builtin_amdgcn_mfma_f32_16x16x32_bf16(af[i], bfg[j], acc[i][j], 0, 0, 0);
        __syncthreads();
    }

#pragma unroll
    for (int i = 0; i < 4; ++i) {
#pragma unroll
        for (int j = 0; j < 4; ++j) {
#pragma unroll
            for (int rr = 0; rr < 4; ++rr) {
                int row = row0 + wm + i * 16 + quad * 4 + rr;
                int col = col0 + wn + j * 16 + l15;
                float v = acc[i][j][rr];
                if constexpr (MODE == MODE_BF16) {
                    v += bias0[col];
                    ((__hip_bfloat16*)C)[(size_t)row * N + col] = F2B(v);
                } else if constexpr (MODE == MODE_OFFAW) {
                    const float* diag = (const float*)extra;
                    v += (col < 96 ? bias0[col] : bias1[col - 96]);
                    v += diag[row] * csum[col];   // q = xw + diag folded in
                    ((__half*)C)[(size_t)row * N + col] = __float2half(v);
                } else if constexpr (MODE == MODE_REVERSE) {
                    v += bias0[col];
                    int tok; win_decode(row, tok);
                    const float* xin = (const float*)extra;   // original x, f32
                    ((float*)C)[(size_t)tok * CDIM + col] = xin[(size_t)tok * CDIM + col] + v;
                } else if constexpr (MODE == MODE_GELU) {
                    v += bias0[col];
                    float t = 0.7978845608028654f * (v + 0.044715f * v * v * v);
                    v = 0.5f * v * (1.0f + tanhf(t));
                    ((__hip_bfloat16*)C)[(size_t)row * N + col] = F2B(v);
                } else {  // MODE_FC2: out = xres + A@fc2 + b, f32 in-place on d_out
                    v += bias0[col];
                    const float* xres = (const float*)extra;
                    v += xres[(size_t)row * CDIM + col];
                    ((float*)C)[(size_t)row * CDIM + col] = v;
                }
            }
        }
    }
}

// ---------------- host launcher ----------------

extern "C" void kernel_launch(void* const* d_in, const int* in_sizes, int n_in,
                              void* d_out, int out_size, void* d_ws, size_t ws_size,
                              hipStream_t stream) {
    // Inputs f32 (reference dtypes); OUTPUT f32 (reference returns float32)
    const float* x      = (const float*)d_in[0];
    const float* mask   = (const float*)d_in[1];
    const float* n1g    = (const float*)d_in[2];
    const float* n1b    = (const float*)d_in[3];
    const float* val_w  = (const float*)d_in[4];
    const float* val_b  = (const float*)d_in[5];
    const float* off_w  = (const float*)d_in[6];
    const float* off_b  = (const float*)d_in[7];
    const float* aw_w   = (const float*)d_in[8];
    const float* aw_b   = (const float*)d_in[9];
    const float* out_w  = (const float*)d_in[10];
    const float* out_b  = (const float*)d_in[11];
    const float* ang    = (const float*)d_in[12];
    const float* anb    = (const float*)d_in[13];
    const float* proj_w = (const float*)d_in[14];
    const float* proj_b = (const float*)d_in[15];
    const float* n2g    = (const float*)d_in[16];
    const float* n2b    = (const float*)d_in[17];
    const float* fc1_w  = (const float*)d_in[18];
    const float* fc1_b  = (const float*)d_in[19];
    const float* fc2_w  = (const float*)d_in[20];
    const float* fc2_b  = (const float*)d_in[21];

    char* ws = (char*)d_ws;
    size_t o = 0;
    auto alloc = [&](size_t bytes) {
        size_t r = o;
        o += (bytes + 255) & ~(size_t)255;
        return r;
    };
    const size_t M = MROWS;

    __hip_bfloat16* valT    = (__hip_bfloat16*)(ws + alloc(256 * 256 * 2));
    __hip_bfloat16* offawT  = (__hip_bfloat16*)(ws + alloc(128 * 256 * 2));
    __hip_bfloat16* outT    = (__hip_bfloat16*)(ws + alloc(256 * 256 * 2));
    __hip_bfloat16* projT   = (__hip_bfloat16*)(ws + alloc(256 * 256 * 2));
    __hip_bfloat16* fc1T    = (__hip_bfloat16*)(ws + alloc(1024 * 256 * 2));
    __hip_bfloat16* fc2T    = (__hip_bfloat16*)(ws + alloc(256 * 1024 * 2));
    float*          csum    = (float*)(ws + alloc(128 * 4));
    float*          diag    = (float*)(ws + alloc(M * 4));
    char*           slab1   = ws + alloc(M * 256 * 2);   // xw -> ai -> a2 -> hin
    char*           slabS   = ws + alloc(M * 128 * 2);   // offaw f16 -> hbuf chunks
    // ws total ~= 40.2 MB.  d_out (f32, 51.4 MB): bf16 scratch (value->attn) then f32 xres -> final
    (void)ws_size; (void)in_sizes; (void)n_in; (void)out_size;

    __hip_bfloat16* xw    = (__hip_bfloat16*)slab1;
    __hip_bfloat16* ai    = (__hip_bfloat16*)slab1;
    __hip_bfloat16* a2    = (__hip_bfloat16*)slab1;
    __hip_bfloat16* hin   = (__hip_bfloat16*)slab1;
    __half*         offaw = (__half*)slabS;
    __hip_bfloat16* hbuf  = (__hip_bfloat16*)slabS;      // MCHUNK x 1024 per chunk
    __hip_bfloat16* value = (__hip_bfloat16*)d_out;      // bf16 scratch (first half)
    __hip_bfloat16* attn  = (__hip_bfloat16*)d_out;      // bf16 scratch (first half)
    float*          xres  = (float*)d_out;               // f32 trunk (full buffer)

    dim3 blk(256);
    auto T = [&](const float* src, __hip_bfloat16* dst, int K, int N) {
        int total = K * N;
        hipLaunchKernelGGL(transpose_kernel, dim3((total + 255) / 256), blk, 0, stream, src, dst, K, N);
    };
    T(val_w, valT, 256, 256);
    T(off_w, offawT, 256, 96);
    T(aw_w, offawT + 96 * 256, 256, 32);
    T(out_w, outT, 256, 256);
    T(proj_w, projT, 256, 256);
    T(fc1_w, fc1T, 256, 1024);
    T(fc2_w, fc2T, 1024, 256);
    hipLaunchKernelGGL(colsum_kernel, dim3(1), dim3(128), 0, stream, offawT, csum);
    hipLaunchKernelGGL(diag_kernel, dim3((MROWS + 255) / 256), blk, 0, stream, mask, diag);

    // 1. xw = LN1(x) windowed          (slab1)
    hipLaunchKernelGGL(ln1_kernel, dim3(MROWS), blk, 0, stream, x, n1g, n1b, xw);
    // 2. value = xw @ val_w + val_b    (d_out bf16 scratch)
    hipLaunchKernelGGL((gemm_bt<MODE_BF16>), dim3(MROWS / 128, 2), blk, 0, stream,
                       xw, valT, 256, 256, val_b, (const float*)nullptr,
                       (void*)value, (const void*)nullptr, (const float*)nullptr);
    // 3. offaw = (xw + diag) @ [off|aw] + bias   (slabS, f16)
    hipLaunchKernelGGL((gemm_bt<MODE_OFFAW>), dim3(MROWS / 128, 1), blk, 0, stream,
                       xw, offawT, 128, 256, off_b, aw_b,
                       (void*)offaw, (const void*)diag, csum);
    // 4. ai = sample(offaw, value)     (slab1; xw dead)
    hipLaunchKernelGGL(sample_kernel, dim3(MROWS), blk, 0, stream, offaw, value, ai);
    // 5. attn = ai @ out_w + out_b     (d_out bf16 scratch; value dead)
    hipLaunchKernelGGL((gemm_bt<MODE_BF16>), dim3(MROWS / 128, 2), blk, 0, stream,
                       ai, outT, 256, 256, out_b, (const float*)nullptr,
                       (void*)attn, (const void*)nullptr, (const float*)nullptr);
    // 6. a2 = LN(LN1(x) + attn)        (slab1; ai dead)
    hipLaunchKernelGGL(ln_a_kernel, dim3(MROWS), blk, 0, stream, x, attn, n1g, n1b, ang, anb, a2);
    // 7. xres = x + reverse(a2 @ proj + b)   (d_out f32, token order; attn dead)
    hipLaunchKernelGGL((gemm_bt<MODE_REVERSE>), dim3(MROWS / 128, 2), blk, 0, stream,
                       a2, projT, 256, 256, proj_b, (const float*)nullptr,
                       (void*)xres, (const void*)x, (const float*)nullptr);
    // 8. hin = LN2(xres)               (slab1; a2 dead)
    hipLaunchKernelGGL(ln2_kernel, dim3(MROWS), blk, 0, stream, xres, n2g, n2b, hin);
    // 9. MLP in 8 row-chunks; fc2 adds xres in-place on d_out (f32->f32, same element)
    for (int c = 0; c < 8; ++c) {
        const __hip_bfloat16* hin_c  = hin  + (size_t)c * MCHUNK * 256;
        float*                out_c  = (float*)d_out + (size_t)c * MCHUNK * 256;
        hipLaunchKernelGGL((gemm_bt<MODE_GELU>), dim3(MCHUNK / 128, 8), blk, 0, stream,
                           hin_c, fc1T, 1024, 256, fc1_b, (const float*)nullptr,
                           (void*)hbuf, (const void*)nullptr, (const float*)nullptr);
        hipLaunchKernelGGL((gemm_bt<MODE_FC2>), dim3(MCHUNK / 128, 2), blk, 0, stream,
                           hbuf, fc2T, 256, 1024, fc2_b, (const float*)nullptr,
                           (void*)out_c, (const void*)out_c, (const float*)nullptr);
    }
}

// Round 7
// 630.864 us; speedup vs baseline: 1.7346x; 1.7346x over previous
//
#include <hip/hip_runtime.h>
#include <hip/hip_bf16.h>
#include <hip/hip_fp16.h>

#define B2F(x) __bfloat162float(x)
#define F2B(x) __float2bfloat16(x)

typedef __bf16 bf16x8 __attribute__((ext_vector_type(8)));
typedef float floatx4 __attribute__((ext_vector_type(4)));

static constexpr int MROWS = 50176;   // 512 windows * 98 tokens
static constexpr int CDIM  = 256;
static constexpr int MCHUNK = 25088;  // MROWS / 2 for MLP chunking

enum { MODE_BF16 = 0, MODE_OFFAW = 1, MODE_REVERSE = 3, MODE_GELU = 4, MODE_FC2 = 5 };

#if defined(__has_builtin)
#if __has_builtin(__builtin_amdgcn_global_load_lds)
#define HAS_GLL 1
#endif
#endif
#ifndef HAS_GLL
#define HAS_GLL 0
#endif

// ---------------- helpers ----------------

__device__ __forceinline__ float block_sum256(float v, float* s4, int tid) {
#pragma unroll
    for (int off = 32; off > 0; off >>= 1) v += __shfl_down(v, off, 64);
    if ((tid & 63) == 0) s4[tid >> 6] = v;
    __syncthreads();
    float r = s4[0] + s4[1] + s4[2] + s4[3];
    __syncthreads();
    return r;
}

__device__ __forceinline__ void win_decode(int r, int& tok) {
    int w = r / 98, n = r - w * 98;
    int dB = w >> 6, hB = (w >> 3) & 7, wB = w & 7;
    int z = n / 49, n2 = n - z * 49, yy = n2 / 7, xx = n2 - yy * 7;
    tok = ((dB * 2 + z) * 56 + hB * 7 + yy) * 56 + wB * 7 + xx;
}

__device__ __forceinline__ float bf2f(unsigned short u) {
    return __uint_as_float(((unsigned)u) << 16);
}

// ---------------- fused weight transpose (f32 -> bf16, (K,N)->(N,K)) ----------------

__global__ __launch_bounds__(256) void transpose_all(
    const float* __restrict__ val_w, const float* __restrict__ off_w,
    const float* __restrict__ aw_w,  const float* __restrict__ out_w,
    const float* __restrict__ proj_w, const float* __restrict__ fc1_w,
    const float* __restrict__ fc2_w,
    __hip_bfloat16* __restrict__ valT, __hip_bfloat16* __restrict__ offawT,
    __hip_bfloat16* __restrict__ outT, __hip_bfloat16* __restrict__ projT,
    __hip_bfloat16* __restrict__ fc1T, __hip_bfloat16* __restrict__ fc2T) {
    int bid = blockIdx.x;
    const float* src; __hip_bfloat16* dst; int K, N, base;
    if (bid < 256)       { src = val_w;  dst = valT;           K = 256;  N = 256;  base = 0; }
    else if (bid < 352)  { src = off_w;  dst = offawT;         K = 256;  N = 96;   base = 256; }
    else if (bid < 384)  { src = aw_w;   dst = offawT + 96*256; K = 256; N = 32;   base = 352; }
    else if (bid < 640)  { src = out_w;  dst = outT;           K = 256;  N = 256;  base = 384; }
    else if (bid < 896)  { src = proj_w; dst = projT;          K = 256;  N = 256;  base = 640; }
    else if (bid < 1920) { src = fc1_w;  dst = fc1T;           K = 256;  N = 1024; base = 896; }
    else                 { src = fc2_w;  dst = fc2T;           K = 1024; N = 256;  base = 1920; }
    int i = (bid - base) * 256 + threadIdx.x;
    if (i >= K * N) return;
    int nn = i / K, kk = i - nn * K;
    dst[(size_t)nn * K + kk] = F2B(src[(size_t)kk * N + nn]);
}

// ---------------- diag (PositionEmbeddingSine) + colsum of off/aw weight ----------------

__global__ __launch_bounds__(256) void diag_colsum_kernel(
    const float* __restrict__ mask, float* __restrict__ diag,
    const __hip_bfloat16* __restrict__ wT, float* __restrict__ csum) {
    if (blockIdx.x == gridDim.x - 1) {
        int n = threadIdx.x;
        if (n < 128) {
            float s = 0.f;
            for (int k = 0; k < 256; ++k) s += B2F(wT[n * 256 + k]);
            csum[n] = s;
        }
        return;
    }
    int r = blockIdx.x * 256 + threadIdx.x;
    int n = r % 98;
    int z = n / 49, n2 = n - z * 49, yy = n2 / 7, xx = n2 - yy * 7;
    const float* mb = mask + (size_t)r * 98;
    float m = mb[z * 49 + yy * 7 + xx];
    float sz = 0.f, sy = 0.f, sx = 0.f;
    for (int k = 0; k <= z; ++k)  sz += mb[k * 49 + yy * 7 + xx];
    for (int k = 0; k <= yy; ++k) sy += mb[z * 49 + k * 7 + xx];
    for (int k = 0; k <= xx; ++k) sx += mb[z * 49 + yy * 7 + k];
    const float PI = 3.14159265358979323846f;
    diag[r] = m * (sinf(sx * m / PI) + sinf(sy * m) + sz * m / PI);
}

// ---------------- LayerNorms ----------------

__global__ __launch_bounds__(256) void ln1_kernel(
    const float* __restrict__ x,
    const float* __restrict__ g, const float* __restrict__ b,
    __hip_bfloat16* __restrict__ xw) {
    __shared__ float s4[4];
    int r = blockIdx.x, c = threadIdx.x;
    int tok; win_decode(r, tok);
    float v = x[(size_t)tok * CDIM + c];
    float mean = block_sum256(v, s4, c) * (1.f / 256.f);
    float d = v - mean;
    float var = block_sum256(d * d, s4, c) * (1.f / 256.f);
    xw[(size_t)r * CDIM + c] = F2B(d * rsqrtf(var + 1e-5f) * g[c] + b[c]);
}

// a2 = LN(xw + attn); in-place safe (reads precede writes across barriers)
__global__ __launch_bounds__(256) void ln_a_kernel(
    const __hip_bfloat16* __restrict__ xw, const __hip_bfloat16* __restrict__ attn,
    const float* __restrict__ g, const float* __restrict__ b,
    __hip_bfloat16* a2) {
    __shared__ float s4[4];
    int r = blockIdx.x, c = threadIdx.x;
    size_t i = (size_t)r * CDIM + c;
    float t = B2F(xw[i]) + B2F(attn[i]);
    float mean = block_sum256(t, s4, c) * (1.f / 256.f);
    float d = t - mean;
    float var = block_sum256(d * d, s4, c) * (1.f / 256.f);
    a2[i] = F2B(d * rsqrtf(var + 1e-5f) * g[c] + b[c]);
}

__global__ __launch_bounds__(256) void ln2_kernel(
    const float* __restrict__ xres,
    const float* __restrict__ g, const float* __restrict__ b,
    __hip_bfloat16* __restrict__ hin) {
    __shared__ float s4[4];
    int r = blockIdx.x, c = threadIdx.x;
    size_t i = (size_t)r * CDIM + c;
    float v = xres[i];
    float mean = block_sum256(v, s4, c) * (1.f / 256.f);
    float d = v - mean;
    float var = block_sum256(d * d, s4, c) * (1.f / 256.f);
    hin[i] = F2B(d * rsqrtf(var + 1e-5f) * g[c] + b[c]);
}

// ---------------- sampling, stage 1: per (row,head) softmax + corner weights/indices ----------------

__global__ __launch_bounds__(256) void prep_kernel(
    const __half* __restrict__ offaw,   // M x 128 (96 off | 32 aw)
    __half* __restrict__ wgt,           // M*8*32 packed corner weights (incl. aw)
    unsigned char* __restrict__ idxb) { // M*8*32 packed spatial indices (0..97)
    int t = blockIdx.x * 256 + threadIdx.x;   // t = r*8 + h
    int r = t >> 3, h = t & 7;
    int n = r % 98;
    int z = n / 49, n2 = n - z * 49, yy = n2 / 7, xx = n2 - yy * 7;
    const __half* orow = offaw + (size_t)r * 128;
    float l0 = __half2float(orow[96 + h * 4 + 0]);
    float l1 = __half2float(orow[96 + h * 4 + 1]);
    float l2 = __half2float(orow[96 + h * 4 + 2]);
    float l3 = __half2float(orow[96 + h * 4 + 3]);
    float mx = fmaxf(fmaxf(l0, l1), fmaxf(l2, l3));
    float e[4];
    e[0] = __expf(l0 - mx); e[1] = __expf(l1 - mx); e[2] = __expf(l2 - mx); e[3] = __expf(l3 - mx);
    float inv = 1.f / (e[0] + e[1] + e[2] + e[3]);
    __half wl[32];
    unsigned char il[32];
#pragma unroll
    for (int p = 0; p < 4; ++p) {
        float ox = __half2float(orow[h * 12 + p * 3 + 0]);
        float oy = __half2float(orow[h * 12 + p * 3 + 1]);
        float oz = __half2float(orow[h * 12 + p * 3 + 2]);
        // px = loc_x*WW - 0.5 == x + off_x (0.5 terms cancel); same for y,z
        float px = (float)xx + ox, py = (float)yy + oy, pz = (float)z + oz;
        float fx0 = floorf(px), fy0 = floorf(py), fz0 = floorf(pz);
        int ix = (int)fx0, iy = (int)fy0, iz = (int)fz0;
        float fx = px - fx0, fy = py - fy0, fz = pz - fz0;
        float wp = e[p] * inv;
        int j = 0;
#pragma unroll
        for (int dz = 0; dz < 2; ++dz) {
            int zi = iz + dz;
            float wz = dz ? fz : 1.f - fz;
#pragma unroll
            for (int dy = 0; dy < 2; ++dy) {
                int yi = iy + dy;
                float wy = dy ? fy : 1.f - fy;
#pragma unroll
                for (int dx = 0; dx < 2; ++dx) {
                    int xi = ix + dx;
                    float wxw = dx ? fx : 1.f - fx;
                    bool valid = (zi >= 0) & (zi < 2) & (yi >= 0) & (yi < 7) & (xi >= 0) & (xi < 7);
                    float wc = valid ? wp * wz * wy * wxw : 0.f;
                    int zc = min(max(zi, 0), 1), yc = min(max(yi, 0), 6), xc = min(max(xi, 0), 6);
                    wl[p * 8 + j] = __float2half(wc);
                    il[p * 8 + j] = (unsigned char)(zc * 49 + yc * 7 + xc);
                    ++j;
                }
            }
        }
    }
    size_t pb = (size_t)t * 32;
    const uint4* ws4 = (const uint4*)wl;
#pragma unroll
    for (int q = 0; q < 4; ++q) ((uint4*)(wgt + pb))[q] = ws4[q];
    const uint4* is4 = (const uint4*)il;
#pragma unroll
    for (int q = 0; q < 2; ++q) ((uint4*)(idxb + pb))[q] = is4[q];
}

// ---------------- sampling, stage 2: gather + weighted sum (4 channels / thread) ----------------

__global__ __launch_bounds__(256) void sample_kernel(
    const __half* __restrict__ wgt, const unsigned char* __restrict__ idxb,
    const __hip_bfloat16* __restrict__ value,   // M x 256
    __hip_bfloat16* __restrict__ ai) {          // M x 256
    int t = threadIdx.x;
    int r = blockIdx.x * 4 + (t >> 6);
    int c4 = t & 63;
    int c0 = c4 * 4;
    int h = c4 >> 3;
    int w = r / 98;
    const __hip_bfloat16* vrow = value + (size_t)(w * 98) * CDIM + c0;
    size_t pb = ((size_t)r * 8 + h) * 32;
    float a0 = 0.f, a1 = 0.f, a2 = 0.f, a3 = 0.f;
#pragma unroll
    for (int p = 0; p < 4; ++p) {
        uint4 wq = *(const uint4*)(wgt + pb + p * 8);
        uint2 iq = *(const uint2*)(idxb + pb + p * 8);
        const __half* wh = (const __half*)&wq;
        const unsigned char* ib = (const unsigned char*)&iq;
#pragma unroll
        for (int j = 0; j < 8; ++j) {
            float wj = __half2float(wh[j]);
            ushort4 v = *(const ushort4*)(vrow + (size_t)ib[j] * CDIM);
            a0 += wj * bf2f(v.x);
            a1 += wj * bf2f(v.y);
            a2 += wj * bf2f(v.z);
            a3 += wj * bf2f(v.w);
        }
    }
    __hip_bfloat16 ob[4] = { F2B(a0), F2B(a1), F2B(a2), F2B(a3) };
    *(ushort4*)(ai + (size_t)r * CDIM + c0) = *(const ushort4*)ob;
}

// ---------------- MFMA GEMM: C[M,N] = A[M,K] * Bt[N,K]^T + bias ----------------

template <int MODE>
__global__ __launch_bounds__(256) void gemm_bt(
    const __hip_bfloat16* __restrict__ A,
    const __hip_bfloat16* __restrict__ Bt,
    const int N, const int K,
    const float* __restrict__ bias0,
    const float* __restrict__ bias1,
    void* C,
    const void* extra,
    const float* __restrict__ csum) {
    __shared__ __align__(16) __hip_bfloat16 As[128 * 32];
    __shared__ __align__(16) __hip_bfloat16 Bs[128 * 32];
    const int tid  = threadIdx.x;
    const int lane = tid & 63;
    const int wave = tid >> 6;
    const int wm = (wave >> 1) * 64;
    const int wn = (wave & 1) * 64;
    const int row0 = blockIdx.x * 128;
    const int col0 = blockIdx.y * 128;
    const int l15 = lane & 15;
    const int quad = lane >> 4;

    floatx4 acc[4][4] = {};

    const int sr = tid >> 2;
    const int sk = (tid & 3) * 8;

    const __hip_bfloat16* Ab = A + (size_t)row0 * K;
    const __hip_bfloat16* Bb = Bt + (size_t)col0 * K;

    for (int k0 = 0; k0 < K; k0 += 32) {
#if HAS_GLL
        // async global->LDS, 16B/lane; lane-order == LDS order (lane writes bytes tid*16)
        __builtin_amdgcn_global_load_lds(
            (const __attribute__((address_space(1))) void*)(Ab + (size_t)sr * K + k0 + sk),
            (__attribute__((address_space(3))) void*)(As + sr * 32 + sk), 16, 0, 0);
        __builtin_amdgcn_global_load_lds(
            (const __attribute__((address_space(1))) void*)(Ab + (size_t)(sr + 64) * K + k0 + sk),
            (__attribute__((address_space(3))) void*)(As + (sr + 64) * 32 + sk), 16, 0, 0);
        __builtin_amdgcn_global_load_lds(
            (const __attribute__((address_space(1))) void*)(Bb + (size_t)sr * K + k0 + sk),
            (__attribute__((address_space(3))) void*)(Bs + sr * 32 + sk), 16, 0, 0);
        __builtin_amdgcn_global_load_lds(
            (const __attribute__((address_space(1))) void*)(Bb + (size_t)(sr + 64) * K + k0 + sk),
            (__attribute__((address_space(3))) void*)(Bs + (sr + 64) * 32 + sk), 16, 0, 0);
#else
        *reinterpret_cast<uint4*>(&As[sr * 32 + sk]) =
            *reinterpret_cast<const uint4*>(&Ab[(size_t)sr * K + k0 + sk]);
        *reinterpret_cast<uint4*>(&As[(sr + 64) * 32 + sk]) =
            *reinterpret_cast<const uint4*>(&Ab[(size_t)(sr + 64) * K + k0 + sk]);
        *reinterpret_cast<uint4*>(&Bs[sr * 32 + sk]) =
            *reinterpret_cast<const uint4*>(&Bb[(size_t)sr * K + k0 + sk]);
        *reinterpret_cast<uint4*>(&Bs[(sr + 64) * 32 + sk]) =
            *reinterpret_cast<const uint4*>(&Bb[(size_t)(sr + 64) * K + k0 + sk]);
#endif
        __syncthreads();   // drains vmcnt (incl. global_load_lds) per barrier semantics
        bf16x8 af[4], bfg[4];
#pragma unroll
        for (int i = 0; i < 4; ++i)
            af[i] = *reinterpret_cast<const bf16x8*>(&As[(wm + i * 16 + l15) * 32 + quad * 8]);
#pragma unroll
        for (int j = 0; j < 4; ++j)
            bfg[j] = *reinterpret_cast<const bf16x8*>(&Bs[(wn + j * 16 + l15) * 32 + quad * 8]);
#pragma unroll
        for (int i = 0; i < 4; ++i)
#pragma unroll
            for (int j = 0; j < 4; ++j)
                acc[i][j] = __builtin_amdgcn_mfma_f32_16x16x32_bf16(af[i], bfg[j], acc[i][j], 0, 0, 0);
        __syncthreads();
    }

#pragma unroll
    for (int i = 0; i < 4; ++i) {
#pragma unroll
        for (int j = 0; j < 4; ++j) {
#pragma unroll
            for (int rr = 0; rr < 4; ++rr) {
                int row = row0 + wm + i * 16 + quad * 4 + rr;
                int col = col0 + wn + j * 16 + l15;
                float v = acc[i][j][rr];
                if constexpr (MODE == MODE_BF16) {
                    v += bias0[col];
                    ((__hip_bfloat16*)C)[(size_t)row * N + col] = F2B(v);
                } else if constexpr (MODE == MODE_OFFAW) {
                    const float* diag = (const float*)extra;
                    v += (col < 96 ? bias0[col] : bias1[col - 96]);
                    v += diag[row] * csum[col];   // q = xw + diag folded in
                    ((__half*)C)[(size_t)row * N + col] = __float2half(v);
                } else if constexpr (MODE == MODE_REVERSE) {
                    v += bias0[col];
                    int tok; win_decode(row, tok);
                    const float* xin = (const float*)extra;   // original x, f32
                    ((float*)C)[(size_t)tok * CDIM + col] = xin[(size_t)tok * CDIM + col] + v;
                } else if constexpr (MODE == MODE_GELU) {
                    v += bias0[col];
                    // gelu_tanh: v * 0.5*(1+tanh(t)) == v * sigmoid(2t), stable via exp(-2t)
                    float t2 = 1.5957691216057308f * (v + 0.044715f * v * v * v);
                    v = v / (1.f + __expf(-t2));
                    ((__hip_bfloat16*)C)[(size_t)row * N + col] = F2B(v);
                } else {  // MODE_FC2: out = xres + A@fc2 + b, f32 in-place on d_out
                    v += bias0[col];
                    const float* xres = (const float*)extra;
                    v += xres[(size_t)row * CDIM + col];
                    ((float*)C)[(size_t)row * CDIM + col] = v;
                }
            }
        }
    }
}

// ---------------- host launcher ----------------

extern "C" void kernel_launch(void* const* d_in, const int* in_sizes, int n_in,
                              void* d_out, int out_size, void* d_ws, size_t ws_size,
                              hipStream_t stream) {
    const float* x      = (const float*)d_in[0];
    const float* mask   = (const float*)d_in[1];
    const float* n1g    = (const float*)d_in[2];
    const float* n1b    = (const float*)d_in[3];
    const float* val_w  = (const float*)d_in[4];
    const float* val_b  = (const float*)d_in[5];
    const float* off_w  = (const float*)d_in[6];
    const float* off_b  = (const float*)d_in[7];
    const float* aw_w   = (const float*)d_in[8];
    const float* aw_b   = (const float*)d_in[9];
    const float* out_w  = (const float*)d_in[10];
    const float* out_b  = (const float*)d_in[11];
    const float* ang    = (const float*)d_in[12];
    const float* anb    = (const float*)d_in[13];
    const float* proj_w = (const float*)d_in[14];
    const float* proj_b = (const float*)d_in[15];
    const float* n2g    = (const float*)d_in[16];
    const float* n2b    = (const float*)d_in[17];
    const float* fc1_w  = (const float*)d_in[18];
    const float* fc1_b  = (const float*)d_in[19];
    const float* fc2_w  = (const float*)d_in[20];
    const float* fc2_b  = (const float*)d_in[21];

    char* ws = (char*)d_ws;
    size_t o = 0;
    auto alloc = [&](size_t bytes) {
        size_t r = o;
        o += (bytes + 255) & ~(size_t)255;
        return r;
    };
    const size_t M = MROWS;
    const size_t WGT_B = M * 8 * 32 * 2;   // 25.7 MB (f16 corner weights)
    const size_t IDX_B = M * 8 * 32;       // 12.8 MB (u8 corner indices)
    const size_t OFF_B = M * 128 * 2;      // 12.8 MB (f16 offaw)

    __hip_bfloat16* valT    = (__hip_bfloat16*)(ws + alloc(256 * 256 * 2));
    __hip_bfloat16* offawT  = (__hip_bfloat16*)(ws + alloc(128 * 256 * 2));
    __hip_bfloat16* outT    = (__hip_bfloat16*)(ws + alloc(256 * 256 * 2));
    __hip_bfloat16* projT   = (__hip_bfloat16*)(ws + alloc(256 * 256 * 2));
    __hip_bfloat16* fc1T    = (__hip_bfloat16*)(ws + alloc(1024 * 256 * 2));
    __hip_bfloat16* fc2T    = (__hip_bfloat16*)(ws + alloc(256 * 1024 * 2));
    float*          csum    = (float*)(ws + alloc(128 * 4));
    float*          diag    = (float*)(ws + alloc(M * 4));
    char*           slab1   = ws + alloc(M * 256 * 2);                 // xw -> a2 -> hin
    char*           region  = ws + alloc(WGT_B + IDX_B + M * 256 * 2); // 64.3 MB multi-use
    // ws total ~= 92 MB (R1 proved >=104 MB mapped). d_out: bf16 scratch then f32 trunk.
    (void)ws_size; (void)in_sizes; (void)n_in; (void)out_size;

    __hip_bfloat16* xw    = (__hip_bfloat16*)slab1;
    __hip_bfloat16* a2    = (__hip_bfloat16*)slab1;                  // in-place over xw
    __hip_bfloat16* hin   = (__hip_bfloat16*)slab1;
    __half*         wgt   = (__half*)region;                         // [0, WGT_B)
    unsigned char*  idxb  = (unsigned char*)(region + WGT_B);        // [WGT_B, +IDX_B)
    __half*         offaw = (__half*)(region + WGT_B + IDX_B);       // prep input
    __hip_bfloat16* ai    = (__hip_bfloat16*)(region + WGT_B + IDX_B); // overwrites offaw
    __hip_bfloat16* hbuf  = (__hip_bfloat16*)region;                 // MLP chunk activation
    __hip_bfloat16* value = (__hip_bfloat16*)d_out;                  // bf16 scratch
    __hip_bfloat16* attn  = (__hip_bfloat16*)d_out;                  // bf16 scratch
    float*          xres  = (float*)d_out;                           // f32 trunk

    dim3 blk(256);
    hipLaunchKernelGGL(transpose_all, dim3(2944), blk, 0, stream,
                       val_w, off_w, aw_w, out_w, proj_w, fc1_w, fc2_w,
                       valT, offawT, outT, projT, fc1T, fc2T);
    hipLaunchKernelGGL(diag_colsum_kernel, dim3(MROWS / 256 + 1), blk, 0, stream,
                       mask, diag, offawT, csum);

    // 1. xw = LN1(x) windowed          (slab1)
    hipLaunchKernelGGL(ln1_kernel, dim3(MROWS), blk, 0, stream, x, n1g, n1b, xw);
    // 2. value = xw @ val_w + val_b    (d_out bf16 scratch)
    hipLaunchKernelGGL((gemm_bt<MODE_BF16>), dim3(MROWS / 128, 2), blk, 0, stream,
                       xw, valT, 256, 256, val_b, (const float*)nullptr,
                       (void*)value, (const void*)nullptr, (const float*)nullptr);
    // 3. offaw = (xw + diag) @ [off|aw] + bias   (region, f16)
    hipLaunchKernelGGL((gemm_bt<MODE_OFFAW>), dim3(MROWS / 128, 1), blk, 0, stream,
                       xw, offawT, 128, 256, off_b, aw_b,
                       (void*)offaw, (const void*)diag, csum);
    // 4a. prep: softmax + corner weights/indices   (region: wgt, idxb)
    hipLaunchKernelGGL(prep_kernel, dim3(MROWS * 8 / 256), blk, 0, stream, offaw, wgt, idxb);
    // 4b. ai = gather-sample(value)    (region, over dead offaw)
    hipLaunchKernelGGL(sample_kernel, dim3(MROWS / 4), blk, 0, stream, wgt, idxb, value, ai);
    // 5. attn = ai @ out_w + out_b     (d_out bf16 scratch; value dead)
    hipLaunchKernelGGL((gemm_bt<MODE_BF16>), dim3(MROWS / 128, 2), blk, 0, stream,
                       ai, outT, 256, 256, out_b, (const float*)nullptr,
                       (void*)attn, (const void*)nullptr, (const float*)nullptr);
    // 6. a2 = LN(xw + attn)            (slab1, in-place over xw)
    hipLaunchKernelGGL(ln_a_kernel, dim3(MROWS), blk, 0, stream, xw, attn, ang, anb, a2);
    // 7. xres = x + reverse(a2 @ proj + b)   (d_out f32, token order; attn dead)
    hipLaunchKernelGGL((gemm_bt<MODE_REVERSE>), dim3(MROWS / 128, 2), blk, 0, stream,
                       a2, projT, 256, 256, proj_b, (const float*)nullptr,
                       (void*)xres, (const void*)x, (const float*)nullptr);
    // 8. hin = LN2(xres)               (slab1; a2 dead)
    hipLaunchKernelGGL(ln2_kernel, dim3(MROWS), blk, 0, stream, xres, n2g, n2b, hin);
    // 9. MLP in 2 row-chunks; fc2 adds xres in-place on d_out (f32, same element)
    for (int c = 0; c < 2; ++c) {
        const __hip_bfloat16* hin_c = hin + (size_t)c * MCHUNK * 256;
        float*                out_c = (float*)d_out + (size_t)c * MCHUNK * 256;
        hipLaunchKernelGGL((gemm_bt<MODE_GELU>), dim3(MCHUNK / 128, 8), blk, 0, stream,
                           hin_c, fc1T, 1024, 256, fc1_b, (const float*)nullptr,
                           (void*)hbuf, (const void*)nullptr, (const float*)nullptr);
        hipLaunchKernelGGL((gemm_bt<MODE_FC2>), dim3(MCHUNK / 128, 2), blk, 0, stream,
                           hbuf, fc2T, 256, 1024, fc2_b, (const float*)nullptr,
                           (void*)out_c, (const void*)out_c, (const float*)nullptr);
    }
}

// Round 8
// 620.048 us; speedup vs baseline: 1.7649x; 1.0174x over previous
//
#include <hip/hip_runtime.h>
#include <hip/hip_bf16.h>
#include <hip/hip_fp16.h>

#define B2F(x) __bfloat162float(x)
#define F2B(x) __float2bfloat16(x)

typedef __bf16 bf16x8 __attribute__((ext_vector_type(8)));
typedef float floatx4 __attribute__((ext_vector_type(4)));

static constexpr int MROWS = 50176;   // 512 windows * 98 tokens
static constexpr int CDIM  = 256;
static constexpr int MCHUNK = 25088;  // MROWS / 2 for MLP chunking

enum { MODE_BF16 = 0, MODE_VALOFFAW = 1, MODE_REVERSE = 3, MODE_GELU = 4, MODE_FC2 = 5 };

#if defined(__has_builtin)
#if __has_builtin(__builtin_amdgcn_global_load_lds)
#define HAS_GLL 1
#endif
#endif
#ifndef HAS_GLL
#define HAS_GLL 0
#endif

// ---------------- helpers ----------------

__device__ __forceinline__ float block_sum256(float v, float* s4, int tid) {
#pragma unroll
    for (int off = 32; off > 0; off >>= 1) v += __shfl_down(v, off, 64);
    if ((tid & 63) == 0) s4[tid >> 6] = v;
    __syncthreads();
    float r = s4[0] + s4[1] + s4[2] + s4[3];
    __syncthreads();
    return r;
}

__device__ __forceinline__ void win_decode(int r, int& tok) {
    int w = r / 98, n = r - w * 98;
    int dB = w >> 6, hB = (w >> 3) & 7, wB = w & 7;
    int z = n / 49, n2 = n - z * 49, yy = n2 / 7, xx = n2 - yy * 7;
    tok = ((dB * 2 + z) * 56 + hB * 7 + yy) * 56 + wB * 7 + xx;
}

__device__ __forceinline__ float bf2f(unsigned short u) {
    return __uint_as_float(((unsigned)u) << 16);
}

// ---------------- fused weight transpose (f32 -> bf16, (K,N)->(N,K)) ----------------

__global__ __launch_bounds__(256) void transpose_all(
    const float* __restrict__ val_w, const float* __restrict__ off_w,
    const float* __restrict__ aw_w,  const float* __restrict__ out_w,
    const float* __restrict__ proj_w, const float* __restrict__ fc1_w,
    const float* __restrict__ fc2_w,
    __hip_bfloat16* __restrict__ valT, __hip_bfloat16* __restrict__ offawT,
    __hip_bfloat16* __restrict__ outT, __hip_bfloat16* __restrict__ projT,
    __hip_bfloat16* __restrict__ fc1T, __hip_bfloat16* __restrict__ fc2T) {
    int bid = blockIdx.x;
    const float* src; __hip_bfloat16* dst; int K, N, base;
    if (bid < 256)       { src = val_w;  dst = valT;           K = 256;  N = 256;  base = 0; }
    else if (bid < 352)  { src = off_w;  dst = offawT;         K = 256;  N = 96;   base = 256; }
    else if (bid < 384)  { src = aw_w;   dst = offawT + 96*256; K = 256; N = 32;   base = 352; }
    else if (bid < 640)  { src = out_w;  dst = outT;           K = 256;  N = 256;  base = 384; }
    else if (bid < 896)  { src = proj_w; dst = projT;          K = 256;  N = 256;  base = 640; }
    else if (bid < 1920) { src = fc1_w;  dst = fc1T;           K = 256;  N = 1024; base = 896; }
    else                 { src = fc2_w;  dst = fc2T;           K = 1024; N = 256;  base = 1920; }
    int i = (bid - base) * 256 + threadIdx.x;
    if (i >= K * N) return;
    int nn = i / K, kk = i - nn * K;
    dst[(size_t)nn * K + kk] = F2B(src[(size_t)kk * N + nn]);
}

// ---------------- diag (PositionEmbeddingSine) + colsum of off/aw weight ----------------

__global__ __launch_bounds__(256) void diag_colsum_kernel(
    const float* __restrict__ mask, float* __restrict__ diag,
    const __hip_bfloat16* __restrict__ wT, float* __restrict__ csum) {
    if (blockIdx.x == gridDim.x - 1) {
        int n = threadIdx.x;
        if (n < 128) {
            float s = 0.f;
            for (int k = 0; k < 256; ++k) s += B2F(wT[n * 256 + k]);
            csum[n] = s;
        }
        return;
    }
    int r = blockIdx.x * 256 + threadIdx.x;
    int n = r % 98;
    int z = n / 49, n2 = n - z * 49, yy = n2 / 7, xx = n2 - yy * 7;
    const float* mb = mask + (size_t)r * 98;
    float m = mb[z * 49 + yy * 7 + xx];
    float sz = 0.f, sy = 0.f, sx = 0.f;
    for (int k = 0; k <= z; ++k)  sz += mb[k * 49 + yy * 7 + xx];
    for (int k = 0; k <= yy; ++k) sy += mb[z * 49 + k * 7 + xx];
    for (int k = 0; k <= xx; ++k) sx += mb[z * 49 + yy * 7 + k];
    const float PI = 3.14159265358979323846f;
    diag[r] = m * (sinf(sx * m / PI) + sinf(sy * m) + sz * m / PI);
}

// ---------------- LayerNorms ----------------

__global__ __launch_bounds__(256) void ln1_kernel(
    const float* __restrict__ x,
    const float* __restrict__ g, const float* __restrict__ b,
    __hip_bfloat16* __restrict__ xw) {
    __shared__ float s4[4];
    int r = blockIdx.x, c = threadIdx.x;
    int tok; win_decode(r, tok);
    float v = x[(size_t)tok * CDIM + c];
    float mean = block_sum256(v, s4, c) * (1.f / 256.f);
    float d = v - mean;
    float var = block_sum256(d * d, s4, c) * (1.f / 256.f);
    xw[(size_t)r * CDIM + c] = F2B(d * rsqrtf(var + 1e-5f) * g[c] + b[c]);
}

__global__ __launch_bounds__(256) void ln_a_kernel(
    const __hip_bfloat16* __restrict__ xw, const __hip_bfloat16* __restrict__ attn,
    const float* __restrict__ g, const float* __restrict__ b,
    __hip_bfloat16* a2) {
    __shared__ float s4[4];
    int r = blockIdx.x, c = threadIdx.x;
    size_t i = (size_t)r * CDIM + c;
    float t = B2F(xw[i]) + B2F(attn[i]);
    float mean = block_sum256(t, s4, c) * (1.f / 256.f);
    float d = t - mean;
    float var = block_sum256(d * d, s4, c) * (1.f / 256.f);
    a2[i] = F2B(d * rsqrtf(var + 1e-5f) * g[c] + b[c]);
}

__global__ __launch_bounds__(256) void ln2_kernel(
    const float* __restrict__ xres,
    const float* __restrict__ g, const float* __restrict__ b,
    __hip_bfloat16* __restrict__ hin) {
    __shared__ float s4[4];
    int r = blockIdx.x, c = threadIdx.x;
    size_t i = (size_t)r * CDIM + c;
    float v = xres[i];
    float mean = block_sum256(v, s4, c) * (1.f / 256.f);
    float d = v - mean;
    float var = block_sum256(d * d, s4, c) * (1.f / 256.f);
    hin[i] = F2B(d * rsqrtf(var + 1e-5f) * g[c] + b[c]);
}

// ---------------- sampling stage 1: per (row,head) softmax + corner weights/indices ----------------

__global__ __launch_bounds__(256) void prep_kernel(
    const __half* __restrict__ offaw,   // M x 128 (96 off | 32 aw)
    __half* __restrict__ wgt,           // M*8*32 packed corner weights (incl. aw)
    unsigned char* __restrict__ idxb) { // M*8*32 packed spatial indices (0..97)
    int t = blockIdx.x * 256 + threadIdx.x;   // t = r*8 + h
    int r = t >> 3, h = t & 7;
    int n = r % 98;
    int z = n / 49, n2 = n - z * 49, yy = n2 / 7, xx = n2 - yy * 7;
    const __half* orow = offaw + (size_t)r * 128;
    float l0 = __half2float(orow[96 + h * 4 + 0]);
    float l1 = __half2float(orow[96 + h * 4 + 1]);
    float l2 = __half2float(orow[96 + h * 4 + 2]);
    float l3 = __half2float(orow[96 + h * 4 + 3]);
    float mx = fmaxf(fmaxf(l0, l1), fmaxf(l2, l3));
    float e[4];
    e[0] = __expf(l0 - mx); e[1] = __expf(l1 - mx); e[2] = __expf(l2 - mx); e[3] = __expf(l3 - mx);
    float inv = 1.f / (e[0] + e[1] + e[2] + e[3]);
    __half wl[32];
    unsigned char il[32];
#pragma unroll
    for (int p = 0; p < 4; ++p) {
        float ox = __half2float(orow[h * 12 + p * 3 + 0]);
        float oy = __half2float(orow[h * 12 + p * 3 + 1]);
        float oz = __half2float(orow[h * 12 + p * 3 + 2]);
        // px = loc_x*WW - 0.5 == x + off_x (0.5 terms cancel); same for y,z
        float px = (float)xx + ox, py = (float)yy + oy, pz = (float)z + oz;
        float fx0 = floorf(px), fy0 = floorf(py), fz0 = floorf(pz);
        int ix = (int)fx0, iy = (int)fy0, iz = (int)fz0;
        float fx = px - fx0, fy = py - fy0, fz = pz - fz0;
        float wp = e[p] * inv;
        int j = 0;
#pragma unroll
        for (int dz = 0; dz < 2; ++dz) {
            int zi = iz + dz;
            float wz = dz ? fz : 1.f - fz;
#pragma unroll
            for (int dy = 0; dy < 2; ++dy) {
                int yi = iy + dy;
                float wy = dy ? fy : 1.f - fy;
#pragma unroll
                for (int dx = 0; dx < 2; ++dx) {
                    int xi = ix + dx;
                    float wxw = dx ? fx : 1.f - fx;
                    bool valid = (zi >= 0) & (zi < 2) & (yi >= 0) & (yi < 7) & (xi >= 0) & (xi < 7);
                    float wc = valid ? wp * wz * wy * wxw : 0.f;
                    int zc = min(max(zi, 0), 1), yc = min(max(yi, 0), 6), xc = min(max(xi, 0), 6);
                    wl[p * 8 + j] = __float2half(wc);
                    il[p * 8 + j] = (unsigned char)(zc * 49 + yc * 7 + xc);
                    ++j;
                }
            }
        }
    }
    size_t pb = (size_t)t * 32;
    const uint4* ws4 = (const uint4*)wl;
#pragma unroll
    for (int q = 0; q < 4; ++q) ((uint4*)(wgt + pb))[q] = ws4[q];
    const uint4* is4 = (const uint4*)il;
#pragma unroll
    for (int q = 0; q < 2; ++q) ((uint4*)(idxb + pb))[q] = is4[q];
}

// ---------------- sampling stage 2: gather + weighted sum (4 channels / thread) ----------------

__global__ __launch_bounds__(256) void sample_kernel(
    const __half* __restrict__ wgt, const unsigned char* __restrict__ idxb,
    const __hip_bfloat16* __restrict__ value,   // M x 256
    __hip_bfloat16* __restrict__ ai) {          // M x 256
    int t = threadIdx.x;
    int r = blockIdx.x * 4 + (t >> 6);
    int c4 = t & 63;
    int c0 = c4 * 4;
    int h = c4 >> 3;
    int w = r / 98;
    const __hip_bfloat16* vrow = value + (size_t)(w * 98) * CDIM + c0;
    size_t pb = ((size_t)r * 8 + h) * 32;
    float a0 = 0.f, a1 = 0.f, a2 = 0.f, a3 = 0.f;
#pragma unroll
    for (int p = 0; p < 4; ++p) {
        uint4 wq = *(const uint4*)(wgt + pb + p * 8);
        uint2 iq = *(const uint2*)(idxb + pb + p * 8);
        const __half* wh = (const __half*)&wq;
        const unsigned char* ib = (const unsigned char*)&iq;
#pragma unroll
        for (int j = 0; j < 8; ++j) {
            float wj = __half2float(wh[j]);
            ushort4 v = *(const ushort4*)(vrow + (size_t)ib[j] * CDIM);
            a0 += wj * bf2f(v.x);
            a1 += wj * bf2f(v.y);
            a2 += wj * bf2f(v.z);
            a3 += wj * bf2f(v.w);
        }
    }
    __hip_bfloat16 ob[4] = { F2B(a0), F2B(a1), F2B(a2), F2B(a3) };
    *(ushort4*)(ai + (size_t)r * CDIM + c0) = *(const ushort4*)ob;
}

// ---------------- MFMA GEMM (double-buffered async staging) ----------------
// C[M,N] = A[M,K] * Bt[N,K]^T + bias, epilogue per MODE.

template <int MODE>
__global__ __launch_bounds__(256) void gemm_bt(
    const __hip_bfloat16* __restrict__ A,
    const __hip_bfloat16* __restrict__ Bt,
    const int N, const int K,
    const float* __restrict__ bias0,
    const float* __restrict__ bias1,
    const float* __restrict__ bias2,
    void* C,
    void* extra,
    const void* extra2,
    const float* __restrict__ csum) {
    __shared__ __align__(16) __hip_bfloat16 As[2][128 * 32];
    __shared__ __align__(16) __hip_bfloat16 Bs[2][128 * 32];
    const int tid  = threadIdx.x;
    const int lane = tid & 63;
    const int wave = tid >> 6;
    const int wm = (wave >> 1) * 64;
    const int wn = (wave & 1) * 64;
    const int row0 = blockIdx.x * 128;
    const int col0 = blockIdx.y * 128;
    const int l15 = lane & 15;
    const int quad = lane >> 4;

    floatx4 acc[4][4] = {};

    const int sr = tid >> 2;
    const int sk = (tid & 3) * 8;

    const __hip_bfloat16* Ab = A + (size_t)row0 * K + sr * (size_t)K + sk;
    const __hip_bfloat16* Bb = Bt + (size_t)col0 * K + sr * (size_t)K + sk;
    const size_t half64 = (size_t)64 * K;

    auto stage = [&](int buf, int k0) {
#if HAS_GLL
        __builtin_amdgcn_global_load_lds(
            (const __attribute__((address_space(1))) void*)(Ab + k0),
            (__attribute__((address_space(3))) void*)(&As[buf][sr * 32 + sk]), 16, 0, 0);
        __builtin_amdgcn_global_load_lds(
            (const __attribute__((address_space(1))) void*)(Ab + half64 + k0),
            (__attribute__((address_space(3))) void*)(&As[buf][(sr + 64) * 32 + sk]), 16, 0, 0);
        __builtin_amdgcn_global_load_lds(
            (const __attribute__((address_space(1))) void*)(Bb + k0),
            (__attribute__((address_space(3))) void*)(&Bs[buf][sr * 32 + sk]), 16, 0, 0);
        __builtin_amdgcn_global_load_lds(
            (const __attribute__((address_space(1))) void*)(Bb + half64 + k0),
            (__attribute__((address_space(3))) void*)(&Bs[buf][(sr + 64) * 32 + sk]), 16, 0, 0);
#else
        *reinterpret_cast<uint4*>(&As[buf][sr * 32 + sk]) = *reinterpret_cast<const uint4*>(Ab + k0);
        *reinterpret_cast<uint4*>(&As[buf][(sr + 64) * 32 + sk]) = *reinterpret_cast<const uint4*>(Ab + half64 + k0);
        *reinterpret_cast<uint4*>(&Bs[buf][sr * 32 + sk]) = *reinterpret_cast<const uint4*>(Bb + k0);
        *reinterpret_cast<uint4*>(&Bs[buf][(sr + 64) * 32 + sk]) = *reinterpret_cast<const uint4*>(Bb + half64 + k0);
#endif
    };

    const int nk = K >> 5;
    stage(0, 0);
    for (int t = 0; t < nk; ++t) {
        __syncthreads();                       // drains vmcnt: buffer t&1 is ready
        if (t + 1 < nk) stage((t + 1) & 1, (t + 1) * 32);   // async fill of other buffer
        const __hip_bfloat16* Asb = As[t & 1];
        const __hip_bfloat16* Bsb = Bs[t & 1];
        bf16x8 af[4], bfg[4];
#pragma unroll
        for (int i = 0; i < 4; ++i)
            af[i] = *reinterpret_cast<const bf16x8*>(&Asb[(wm + i * 16 + l15) * 32 + quad * 8]);
#pragma unroll
        for (int j = 0; j < 4; ++j)
            bfg[j] = *reinterpret_cast<const bf16x8*>(&Bsb[(wn + j * 16 + l15) * 32 + quad * 8]);
#pragma unroll
        for (int i = 0; i < 4; ++i)
#pragma unroll
            for (int j = 0; j < 4; ++j)
                acc[i][j] = __builtin_amdgcn_mfma_f32_16x16x32_bf16(af[i], bfg[j], acc[i][j], 0, 0, 0);
    }

#pragma unroll
    for (int i = 0; i < 4; ++i) {
#pragma unroll
        for (int j = 0; j < 4; ++j) {
#pragma unroll
            for (int rr = 0; rr < 4; ++rr) {
                int row = row0 + wm + i * 16 + quad * 4 + rr;
                int col = col0 + wn + j * 16 + l15;
                float v = acc[i][j][rr];
                if constexpr (MODE == MODE_BF16) {
                    v += bias0[col];
                    ((__hip_bfloat16*)C)[(size_t)row * N + col] = F2B(v);
                } else if constexpr (MODE == MODE_VALOFFAW) {
                    // cols [0,256): value (bf16, ld 256). cols [256,384): offaw (f16, ld 128)
                    if (col < 256) {
                        v += bias0[col];
                        ((__hip_bfloat16*)C)[(size_t)row * 256 + col] = F2B(v);
                    } else {
                        int c2 = col - 256;
                        const float* diag = (const float*)extra2;
                        v += (c2 < 96 ? bias1[c2] : bias2[c2 - 96]);
                        v += diag[row] * csum[c2];   // q = xw + diag folded in
                        ((__half*)extra)[(size_t)row * 128 + c2] = __float2half(v);
                    }
                } else if constexpr (MODE == MODE_REVERSE) {
                    v += bias0[col];
                    int tok; win_decode(row, tok);
                    const float* xin = (const float*)extra2;   // original x, f32
                    ((float*)C)[(size_t)tok * CDIM + col] = xin[(size_t)tok * CDIM + col] + v;
                } else if constexpr (MODE == MODE_GELU) {
                    v += bias0[col];
                    // gelu_tanh == v * sigmoid(2t)
                    float t2 = 1.5957691216057308f * (v + 0.044715f * v * v * v);
                    v = v / (1.f + __expf(-t2));
                    ((__hip_bfloat16*)C)[(size_t)row * N + col] = F2B(v);
                } else {  // MODE_FC2: out = xres + A@fc2 + b, f32 in-place on d_out
                    v += bias0[col];
                    const float* xres = (const float*)extra2;
                    v += xres[(size_t)row * CDIM + col];
                    ((float*)C)[(size_t)row * CDIM + col] = v;
                }
            }
        }
    }
}

// ---------------- host launcher ----------------

extern "C" void kernel_launch(void* const* d_in, const int* in_sizes, int n_in,
                              void* d_out, int out_size, void* d_ws, size_t ws_size,
                              hipStream_t stream) {
    const float* x      = (const float*)d_in[0];
    const float* mask   = (const float*)d_in[1];
    const float* n1g    = (const float*)d_in[2];
    const float* n1b    = (const float*)d_in[3];
    const float* val_w  = (const float*)d_in[4];
    const float* val_b  = (const float*)d_in[5];
    const float* off_w  = (const float*)d_in[6];
    const float* off_b  = (const float*)d_in[7];
    const float* aw_w   = (const float*)d_in[8];
    const float* aw_b   = (const float*)d_in[9];
    const float* out_w  = (const float*)d_in[10];
    const float* out_b  = (const float*)d_in[11];
    const float* ang    = (const float*)d_in[12];
    const float* anb    = (const float*)d_in[13];
    const float* proj_w = (const float*)d_in[14];
    const float* proj_b = (const float*)d_in[15];
    const float* n2g    = (const float*)d_in[16];
    const float* n2b    = (const float*)d_in[17];
    const float* fc1_w  = (const float*)d_in[18];
    const float* fc1_b  = (const float*)d_in[19];
    const float* fc2_w  = (const float*)d_in[20];
    const float* fc2_b  = (const float*)d_in[21];

    char* ws = (char*)d_ws;
    size_t o = 0;
    auto alloc = [&](size_t bytes) {
        size_t r = o;
        o += (bytes + 255) & ~(size_t)255;
        return r;
    };
    const size_t M = MROWS;
    const size_t WGT_B = M * 8 * 32 * 2;   // 25.7 MB (f16 corner weights)
    const size_t IDX_B = M * 8 * 32;       // 12.8 MB (u8 corner indices)

    __hip_bfloat16* valT    = (__hip_bfloat16*)(ws + alloc(256 * 256 * 2));
    __hip_bfloat16* offawT  = (__hip_bfloat16*)(ws + alloc(128 * 256 * 2));  // contiguous after valT
    __hip_bfloat16* outT    = (__hip_bfloat16*)(ws + alloc(256 * 256 * 2));
    __hip_bfloat16* projT   = (__hip_bfloat16*)(ws + alloc(256 * 256 * 2));
    __hip_bfloat16* fc1T    = (__hip_bfloat16*)(ws + alloc(1024 * 256 * 2));
    __hip_bfloat16* fc2T    = (__hip_bfloat16*)(ws + alloc(256 * 1024 * 2));
    float*          csum    = (float*)(ws + alloc(128 * 4));
    float*          diag    = (float*)(ws + alloc(M * 4));
    char*           slab1   = ws + alloc(M * 256 * 2);                 // xw -> a2 -> hin
    char*           region  = ws + alloc(WGT_B + IDX_B + M * 256 * 2); // 64.3 MB multi-use
    (void)ws_size; (void)in_sizes; (void)n_in; (void)out_size;

    __hip_bfloat16* xw    = (__hip_bfloat16*)slab1;
    __hip_bfloat16* a2    = (__hip_bfloat16*)slab1;
    __hip_bfloat16* hin   = (__hip_bfloat16*)slab1;
    __half*         wgt   = (__half*)region;
    unsigned char*  idxb  = (unsigned char*)(region + WGT_B);
    __half*         offaw = (__half*)(region + WGT_B + IDX_B);
    __hip_bfloat16* ai    = (__hip_bfloat16*)(region + WGT_B + IDX_B);
    __hip_bfloat16* hbuf  = (__hip_bfloat16*)region;                  // MLP chunk activation
    __hip_bfloat16* value = (__hip_bfloat16*)d_out;                   // bf16 scratch
    __hip_bfloat16* attn  = (__hip_bfloat16*)d_out;                   // bf16 scratch
    float*          xres  = (float*)d_out;                            // f32 trunk

    dim3 blk(256);
    hipLaunchKernelGGL(transpose_all, dim3(2944), blk, 0, stream,
                       val_w, off_w, aw_w, out_w, proj_w, fc1_w, fc2_w,
                       valT, offawT, outT, projT, fc1T, fc2T);
    hipLaunchKernelGGL(diag_colsum_kernel, dim3(MROWS / 256 + 1), blk, 0, stream,
                       mask, diag, offawT, csum);

    // 1. xw = LN1(x) windowed          (slab1)
    hipLaunchKernelGGL(ln1_kernel, dim3(MROWS), blk, 0, stream, x, n1g, n1b, xw);
    // 2+3 merged. N=384 over [valT|offawT]: value -> d_out bf16, offaw -> region f16
    hipLaunchKernelGGL((gemm_bt<MODE_VALOFFAW>), dim3(MROWS / 128, 3), blk, 0, stream,
                       xw, valT, 384, 256, val_b, off_b, aw_b,
                       (void*)value, (void*)offaw, (const void*)diag, csum);
    // 4a. prep: softmax + corner weights/indices   (region: wgt, idxb)
    hipLaunchKernelGGL(prep_kernel, dim3(MROWS * 8 / 256), blk, 0, stream, offaw, wgt, idxb);
    // 4b. ai = gather-sample(value)    (region, over dead offaw)
    hipLaunchKernelGGL(sample_kernel, dim3(MROWS / 4), blk, 0, stream, wgt, idxb, value, ai);
    // 5. attn = ai @ out_w + out_b     (d_out bf16 scratch; value dead)
    hipLaunchKernelGGL((gemm_bt<MODE_BF16>), dim3(MROWS / 128, 2), blk, 0, stream,
                       ai, outT, 256, 256, out_b, (const float*)nullptr, (const float*)nullptr,
                       (void*)attn, (void*)nullptr, (const void*)nullptr, (const float*)nullptr);
    // 6. a2 = LN(xw + attn)            (slab1, in-place over xw)
    hipLaunchKernelGGL(ln_a_kernel, dim3(MROWS), blk, 0, stream, xw, attn, ang, anb, a2);
    // 7. xres = x + reverse(a2 @ proj + b)   (d_out f32, token order; attn dead)
    hipLaunchKernelGGL((gemm_bt<MODE_REVERSE>), dim3(MROWS / 128, 2), blk, 0, stream,
                       a2, projT, 256, 256, proj_b, (const float*)nullptr, (const float*)nullptr,
                       (void*)xres, (void*)nullptr, (const void*)x, (const float*)nullptr);
    // 8. hin = LN2(xres)               (slab1; a2 dead)
    hipLaunchKernelGGL(ln2_kernel, dim3(MROWS), blk, 0, stream, xres, n2g, n2b, hin);
    // 9. MLP in 2 row-chunks; fc2 adds xres in-place on d_out (f32, same element)
    for (int c = 0; c < 2; ++c) {
        const __hip_bfloat16* hin_c = hin + (size_t)c * MCHUNK * 256;
        float*                out_c = (float*)d_out + (size_t)c * MCHUNK * 256;
        hipLaunchKernelGGL((gemm_bt<MODE_GELU>), dim3(MCHUNK / 128, 8), blk, 0, stream,
                           hin_c, fc1T, 1024, 256, fc1_b, (const float*)nullptr, (const float*)nullptr,
                           (void*)hbuf, (void*)nullptr, (const void*)nullptr, (const float*)nullptr);
        hipLaunchKernelGGL((gemm_bt<MODE_FC2>), dim3(MCHUNK / 128, 2), blk, 0, stream,
                           hbuf, fc2T, 256, 1024, fc2_b, (const float*)nullptr, (const float*)nullptr,
                           (void*)out_c, (void*)nullptr, (const void*)out_c, (const float*)nullptr);
    }
}